// Round 13
// baseline (273.776 us; speedup 1.0000x reference)
//
#include <hip/hip_runtime.h>
#include <hip/hip_bf16.h>

// Attn: energies = out_state @ (history @ W.T).T ; softmax rows.
// S2=S1=4096, N=1024. fp32 in/out. bf16 hi/lo GEMM, 3 products
// (Ah.Bh + Al.Bh + Ah.Bl), 4 separate arrays.
// R22 post-mortem: 7th near-null; the 2-barrier lockstep slab's overhead is
//   composite (m233) -- only the full 8-phase template escapes (m218/m196).
//   R12 was closest but had sched_barrier(0) pins (m141: -42%) and no lead.
// R23: faithful 8-phase port for gemm_e via VIRTUAL-K: 48 K-tiles of 64;
//   tile t in [0,16)=(Ah,Bh), [16,32)=(Al,Bh), [32,48)=(Ah,Bl) -- pointer
//   select per tile, 2 panels/tile -> NBUF=2 + half-unit staging + 4-7 phase
//   lead. Per K-tile: 4 phases {reads(12/4/8/0) + stage 1 half-unit ->
//   barrier -> lgkm0 -> setprio 16 MFMA -> barrier}; boundary vmcnt(2)
//   counted (never 0 until tail). Zero-conflict fragment LDS (= T2's goal).
//   NO sched_barrier. gemm_p/splits/softmax untouched.
//   Wait-arithmetic: stage order per tile t: ph1 Ah1(t+1), ph2 Bh0(t+1),
//   ph3 Bh1(t+1), ph4 Ah0(t+2). In-flight at boundary = 10 loads; vmcnt(2)
//   drains the 8 oldest (= all of t+1), leaves Ah0(t+2). Unit lead 2-7
//   phases. WAR: unit staged into nb only after all its readers' lgkm0 +
//   barrier (reads of a buffer end at its ph3).

typedef __bf16 bf16x8 __attribute__((ext_vector_type(8)));
typedef float f32x4 __attribute__((ext_vector_type(4)));
typedef unsigned short u16x4 __attribute__((ext_vector_type(4)));

__device__ __forceinline__ unsigned short f2bf(float x) {
  unsigned int u = __float_as_uint(x);
  u += 0x7fffu + ((u >> 16) & 1u);   // RNE
  return (unsigned short)(u >> 16);
}
__device__ __forceinline__ float bf2f(unsigned short h) {
  return __uint_as_float(((unsigned int)h) << 16);
}

__device__ __forceinline__ void async_copy_16(void* lds, const void* gsrc) {
  __builtin_amdgcn_global_load_lds(
      (const __attribute__((address_space(1))) void*)gsrc,
      (__attribute__((address_space(3))) void*)lds, 16, 0, 0);
}

__device__ __forceinline__ void barrier_fenced() {
  asm volatile("" ::: "memory");
  __builtin_amdgcn_s_barrier();
  asm volatile("" ::: "memory");
}

// Fused split: fp32 X[rows x 1024] -> Yh, Yl bf16 (hi + residual-lo) for
// history (4096), W (1024), out_state (4096) in one launch (grid 9216).
__global__ __launch_bounds__(256)
void split_all(const float* __restrict__ H, const float* __restrict__ W,
               const float* __restrict__ OS,
               unsigned short* __restrict__ Hh, unsigned short* __restrict__ Hl,
               unsigned short* __restrict__ Wh, unsigned short* __restrict__ Wl,
               unsigned short* __restrict__ Ah, unsigned short* __restrict__ Al) {
  const int b = blockIdx.x;
  const float* X; unsigned short *Yh, *Yl; size_t row;
  if (b < 4096)      { X = H;  Yh = Hh; Yl = Hl; row = b; }
  else if (b < 5120) { X = W;  Yh = Wh; Yl = Wl; row = b - 4096; }
  else               { X = OS; Yh = Ah; Yl = Al; row = b - 5120; }
  const int c4 = threadIdx.x;
  float4 x = ((const float4*)(X + row * 1024))[c4];
  float xs[4] = {x.x, x.y, x.z, x.w};
  u16x4 h, l;
#pragma unroll
  for (int i = 0; i < 4; ++i) {
    unsigned short hh = f2bf(xs[i]);
    h[i] = hh;
    l[i] = f2bf(xs[i] - bf2f(hh));
  }
  ((u16x4*)(Yh + row * 1024))[c4] = h;
  ((u16x4*)(Yl + row * 1024))[c4] = l;
}

// ================= stage-2: energies (8-phase template, virtual-K) =========
// C[4096,4096]. 256x256 tile, 8 waves (wm=w>>2 in {0,1}, wn=w&3 in 0..3),
// wave tile 128x64, 16x16x32 MFMA, acc[8][4] f32x4.
// LDS per side: [buf:2][half:2][group:8][kk:2][64 lanes x 16B] = 64 KB.
// Stage unit = one (side, half): 16 DMAs (wave w does group g=w, kk=0,1).
// Reads: A-frag(mt,kk) at [buf][wm][mt][kk][lane]; B-frag(nt,kk) at
// [buf][wn>>1][(wn&1)*4+nt][kk][lane]. All reads base+lane*16: 0 conflicts.
__global__ __launch_bounds__(512, 2)
void gemm_e(const unsigned short* __restrict__ Ah, const unsigned short* __restrict__ Al,
            const unsigned short* __restrict__ Bh, const unsigned short* __restrict__ Bl,
            float* __restrict__ C) {
  constexpr int NVT = 48;                 // virtual K-tiles of 64
  __shared__ unsigned short AS[2 * 2 * 8 * 1024];   // 64 KB
  __shared__ unsigned short BS[2 * 2 * 8 * 1024];   // 64 KB

  const int tid = threadIdx.x;
  const int w = tid >> 6;
  const int lane = tid & 63;
  const int wm = w >> 2, wn = w & 3;
  const int lr = lane & 15;
  const int ls = lane >> 4;

  // XCD swizzle: grid 256 = 8 XCDs x 32; bijective
  const int id = blockIdx.x;
  const int xcd = id & 7;
  const int j = id >> 3;
  const int bm = ((xcd % 4) * 4 + (j % 4)) * 256;
  const int bn = ((xcd / 4) * 8 + (j / 4)) * 256;

  // per-lane staging source pointers (wave w stages row-group w of each half)
  const unsigned short *pah0, *pah1, *pal0, *pal1, *pbh0, *pbh1, *pbl0, *pbl1;
  {
    const size_t ra = (size_t)(bm + w * 16 + lr) * 1024 + ls * 8;
    pah0 = Ah + ra; pah1 = pah0 + (size_t)128 * 1024;
    pal0 = Al + ra; pal1 = pal0 + (size_t)128 * 1024;
    const size_t rb = (size_t)(bn + w * 16 + lr) * 1024 + ls * 8;
    pbh0 = Bh + rb; pbh1 = pbh0 + (size_t)128 * 1024;
    pbl0 = Bl + rb; pbl1 = pbl0 + (size_t)128 * 1024;
  }

  f32x4 acc[8][4] = {};

  // stage one half-unit of virtual tile vt (2 DMAs per wave: kk=0,1)
  auto stageA = [&](int buf, int hf, int vt) {
    const int p = vt >> 4, kt = vt & 15;
    const unsigned short* s = (p == 1) ? (hf ? pal1 : pal0) : (hf ? pah1 : pah0);
    s += kt * 64;
    unsigned short* d = &AS[((buf * 2 + hf) * 8 + w) * 1024];
    async_copy_16(d, s);                 // kk0
    async_copy_16(d + 512, s + 32);      // kk1
  };
  auto stageB = [&](int buf, int hf, int vt) {
    const int p = vt >> 4, kt = vt & 15;
    const unsigned short* s = (p == 2) ? (hf ? pbl1 : pbl0) : (hf ? pbh1 : pbh0);
    s += kt * 64;
    unsigned short* d = &BS[((buf * 2 + hf) * 8 + w) * 1024];
    async_copy_16(d, s);
    async_copy_16(d + 512, s + 32);
  };
  auto LDA = [&](int buf, int mt, int kk) {
    return *(const bf16x8*)&AS[((buf * 2 + wm) * 8 + mt) * 1024 + kk * 512 + lane * 8];
  };
  auto LDB = [&](int buf, int nt, int kk) {
    return *(const bf16x8*)&BS[((buf * 2 + (wn >> 1)) * 8 + (wn & 1) * 4 + nt) * 1024 + kk * 512 + lane * 8];
  };

  // prologue: tile 0 fully staged + Ah0(tile 1) in flight
  stageA(0, 0, 0); stageA(0, 1, 0); stageB(0, 0, 0); stageB(0, 1, 0);
  stageA(1, 0, 1);
  asm volatile("s_waitcnt vmcnt(2)" ::: "memory");
  barrier_fenced();

#pragma unroll 1
  for (int t = 0; t < NVT; ++t) {
    const int buf = t & 1, nb = buf ^ 1;
    bf16x8 a[4][2], a2[4][2], b[4][2];

    // ---- ph1: reads A[wm][m0..4)x{kk0,kk1} (8) + B kk0 (4); stage Ah1(t+1);
    //      barrier; lgkm0; 16 MFMA (m0-3 x n x kk0); barrier.
#pragma unroll
    for (int mt = 0; mt < 4; ++mt)
#pragma unroll
      for (int kk = 0; kk < 2; ++kk) a[mt][kk] = LDA(buf, mt, kk);
#pragma unroll
    for (int nt = 0; nt < 4; ++nt) b[nt][0] = LDB(buf, nt, 0);
    if (t + 1 < NVT) stageA(nb, 1, t + 1);
    asm volatile("s_waitcnt lgkmcnt(8)" ::: "memory");
    barrier_fenced();
    asm volatile("s_waitcnt lgkmcnt(0)" ::: "memory");
    __builtin_amdgcn_s_setprio(1);
#pragma unroll
    for (int mt = 0; mt < 4; ++mt)
#pragma unroll
      for (int nt = 0; nt < 4; ++nt)
        acc[mt][nt] = __builtin_amdgcn_mfma_f32_16x16x32_bf16(a[mt][0], b[nt][0], acc[mt][nt], 0, 0, 0);
    __builtin_amdgcn_s_setprio(0);
    barrier_fenced();

    // ---- ph2: reads B kk1 (4); stage Bh0(t+1); 16 MFMA (m0-3 x kk1) ----
#pragma unroll
    for (int nt = 0; nt < 4; ++nt) b[nt][1] = LDB(buf, nt, 1);
    if (t + 1 < NVT) stageB(nb, 0, t + 1);
    barrier_fenced();
    asm volatile("s_waitcnt lgkmcnt(0)" ::: "memory");
    __builtin_amdgcn_s_setprio(1);
#pragma unroll
    for (int mt = 0; mt < 4; ++mt)
#pragma unroll
      for (int nt = 0; nt < 4; ++nt)
        acc[mt][nt] = __builtin_amdgcn_mfma_f32_16x16x32_bf16(a[mt][1], b[nt][1], acc[mt][nt], 0, 0, 0);
    __builtin_amdgcn_s_setprio(0);
    barrier_fenced();

    // ---- ph3: reads A m4..8 both kk (8); stage Bh1(t+1); 16 MFMA (m4-7 kk0)
#pragma unroll
    for (int mt = 0; mt < 4; ++mt)
#pragma unroll
      for (int kk = 0; kk < 2; ++kk) a2[mt][kk] = LDA(buf, 4 + mt, kk);
    if (t + 1 < NVT) stageB(nb, 1, t + 1);
    barrier_fenced();
    asm volatile("s_waitcnt lgkmcnt(0)" ::: "memory");
    __builtin_amdgcn_s_setprio(1);
#pragma unroll
    for (int mt = 0; mt < 4; ++mt)
#pragma unroll
      for (int nt = 0; nt < 4; ++nt)
        acc[4 + mt][nt] = __builtin_amdgcn_mfma_f32_16x16x32_bf16(a2[mt][0], b[nt][0], acc[4 + mt][nt], 0, 0, 0);
    __builtin_amdgcn_s_setprio(0);
    barrier_fenced();

    // ---- ph4: stage Ah0(t+2) into buf (its readers drained at ph3);
    //      16 MFMA (m4-7 kk1, regs from ph3); boundary counted vmcnt.
    if (t + 2 < NVT) stageA(buf, 0, t + 2);
    __builtin_amdgcn_s_setprio(1);
#pragma unroll
    for (int mt = 0; mt < 4; ++mt)
#pragma unroll
      for (int nt = 0; nt < 4; ++nt)
        acc[4 + mt][nt] = __builtin_amdgcn_mfma_f32_16x16x32_bf16(a2[mt][1], b[nt][1], acc[4 + mt][nt], 0, 0, 0);
    __builtin_amdgcn_s_setprio(0);
    if (t < NVT - 2)
      asm volatile("s_waitcnt vmcnt(2)" ::: "memory");   // drain tile t+1, keep Ah0(t+2)
    else
      asm volatile("s_waitcnt vmcnt(0)" ::: "memory");   // tail
    barrier_fenced();
  }

  // Epilogue. 16x16 C/D (m89): col = lane&15, row = (lane>>4)*4 + reg.
  const int cm0 = bm + wm * 128;
  const int cn0 = bn + wn * 64;
#pragma unroll
  for (int mt = 0; mt < 8; ++mt)
#pragma unroll
    for (int nt = 0; nt < 4; ++nt) {
      const int col = cn0 + nt * 16 + lr;
      const int row0 = cm0 + mt * 16 + ls * 4;
#pragma unroll
      for (int r = 0; r < 4; ++r)
        C[(size_t)(row0 + r) * 4096 + col] = acc[mt][nt][r];
    }
}

// ==================== stage-1: proj (R20-exact, split-K=2) ==================
__global__ __launch_bounds__(512, 2)
void gemm_p(const unsigned short* __restrict__ Ah, const unsigned short* __restrict__ Al,
            const unsigned short* __restrict__ Bh, const unsigned short* __restrict__ Bl,
            float* __restrict__ Cpart) {
  constexpr int MT = 4, NT = 2, NTILES = 16;
  __shared__ unsigned short AhS[2][128 * 32];
  __shared__ unsigned short AlS[2][128 * 32];
  __shared__ unsigned short BhS[2][128 * 32];
  __shared__ unsigned short BlS[2][128 * 32];

  const int tid = threadIdx.x;
  const int w = tid >> 6;
  const int lane = tid & 63;
  const int wm = w >> 2, wn = w & 3;
  const int lr = lane & 15;
  const int ls = lane >> 4;

  const int kh = blockIdx.x >> 8;
  const int rid = blockIdx.x & 255;
  const int xcd = rid & 7;
  const int j = rid >> 3;
  const int bm = ((xcd % 4) * 8 + (j % 8)) * 128;
  const int bn = ((xcd / 4) * 4 + (j / 8)) * 128;
  const int koff = kh * 512;
  float* __restrict__ C = Cpart + (size_t)kh * 4096 * 1024;

  const unsigned short *pah, *pal, *pbh, *pbl;
  {
    const size_t ra = (size_t)(bm + w * 16 + lr) * 1024 + koff + ls * 8;
    pah = Ah + ra; pal = Al + ra;
    const size_t rb = (size_t)(bn + w * 16 + lr) * 1024 + koff + ls * 8;
    pbh = Bh + rb; pbl = Bl + rb;
  }

  f32x4 acc[MT][NT] = {};

  auto stage_all = [&](int buf, int t) {
    async_copy_16(&AhS[buf][w * 512], pah + t * 32);
    async_copy_16(&BhS[buf][w * 512], pbh + t * 32);
    async_copy_16(&BlS[buf][w * 512], pbl + t * 32);
    async_copy_16(&AlS[buf][w * 512], pal + t * 32);
  };
  auto LDAh = [&](int buf, int g) { return *(const bf16x8*)&AhS[buf][g * 512 + ls * 128 + lr * 8]; };
  auto LDAl = [&](int buf, int g) { return *(const bf16x8*)&AlS[buf][g * 512 + ls * 128 + lr * 8]; };
  auto LDBh = [&](int buf, int g) { return *(const bf16x8*)&BhS[buf][g * 512 + ls * 128 + lr * 8]; };
  auto LDBl = [&](int buf, int g) { return *(const bf16x8*)&BlS[buf][g * 512 + ls * 128 + lr * 8]; };

  stage_all(0, 0);
  asm volatile("s_waitcnt vmcnt(0)" ::: "memory");
  barrier_fenced();

#pragma unroll 1
  for (int t = 0; t < NTILES; ++t) {
    const int buf = t & 1, nb = buf ^ 1;
    const bool st = (t + 1 < NTILES);
    bf16x8 ah[4], al[4], bh[2], bl[2];

#pragma unroll
    for (int mt = 0; mt < 4; ++mt) ah[mt] = LDAh(buf, wm * MT + mt);
#pragma unroll
    for (int nt = 0; nt < 2; ++nt) bh[nt] = LDBh(buf, wn * NT + nt);
#pragma unroll
    for (int nt = 0; nt < 2; ++nt) bl[nt] = LDBl(buf, wn * NT + nt);
    if (st) stage_all(nb, t + 1);
    barrier_fenced();
    asm volatile("s_waitcnt lgkmcnt(0)" ::: "memory");
    __builtin_amdgcn_s_setprio(1);
#pragma unroll
    for (int mt = 0; mt < 4; ++mt)
#pragma unroll
      for (int nt = 0; nt < 2; ++nt)
        acc[mt][nt] = __builtin_amdgcn_mfma_f32_16x16x32_bf16(ah[mt], bh[nt], acc[mt][nt], 0, 0, 0);
#pragma unroll
    for (int mt = 0; mt < 4; ++mt)
#pragma unroll
      for (int nt = 0; nt < 2; ++nt)
        acc[mt][nt] = __builtin_amdgcn_mfma_f32_16x16x32_bf16(ah[mt], bl[nt], acc[mt][nt], 0, 0, 0);
    __builtin_amdgcn_s_setprio(0);
    barrier_fenced();

#pragma unroll
    for (int mt = 0; mt < 4; ++mt) al[mt] = LDAl(buf, wm * MT + mt);
    barrier_fenced();
    asm volatile("s_waitcnt lgkmcnt(0)" ::: "memory");
    __builtin_amdgcn_s_setprio(1);
#pragma unroll
    for (int mt = 0; mt < 4; ++mt)
#pragma unroll
      for (int nt = 0; nt < 2; ++nt)
        acc[mt][nt] = __builtin_amdgcn_mfma_f32_16x16x32_bf16(al[mt], bh[nt], acc[mt][nt], 0, 0, 0);
    __builtin_amdgcn_s_setprio(0);

    asm volatile("s_waitcnt vmcnt(0) lgkmcnt(0)" ::: "memory");
    barrier_fenced();
  }

  const int cm0 = bm + wm * 64;
  const int cn0 = bn + wn * 32;
#pragma unroll
  for (int mt = 0; mt < MT; ++mt)
#pragma unroll
    for (int nt = 0; nt < NT; ++nt) {
      const int col = cn0 + nt * 16 + lr;
      const int row0 = cm0 + mt * 16 + ls * 4;
#pragma unroll
      for (int r = 0; r < 4; ++r)
        C[(size_t)(row0 + r) * 1024 + col] = acc[mt][nt][r];
    }
}

// P = Pa + Pb; split hi/lo into Ph, Pl. Row per block.
__global__ __launch_bounds__(256)
void reduce_split(const float* __restrict__ Pa, const float* __restrict__ Pb,
                  unsigned short* __restrict__ Ph, unsigned short* __restrict__ Pl) {
  const size_t row = blockIdx.x;
  const int c4 = threadIdx.x;
  float4 a = ((const float4*)(Pa + row * 1024))[c4];
  float4 b = ((const float4*)(Pb + row * 1024))[c4];
  float s[4] = {a.x + b.x, a.y + b.y, a.z + b.z, a.w + b.w};
  u16x4 h, l;
#pragma unroll
  for (int i = 0; i < 4; ++i) {
    unsigned short hh = f2bf(s[i]);
    h[i] = hh;
    l[i] = f2bf(s[i] - bf2f(hh));
  }
  ((u16x4*)(Ph + row * 1024))[c4] = h;
  ((u16x4*)(Pl + row * 1024))[c4] = l;
}

// In-place row softmax, N=4096, one block per row, 16 floats/thread in regs.
__global__ __launch_bounds__(256)
void softmax_inplace(float* __restrict__ C, int N) {
  float4* r4 = (float4*)(C + (size_t)blockIdx.x * N);
  const int t = threadIdx.x;
  float4 v[4];
  float mx = -3.0e38f;
#pragma unroll
  for (int i = 0; i < 4; ++i) {
    v[i] = r4[t + i * 256];
    mx = fmaxf(mx, fmaxf(fmaxf(v[i].x, v[i].y), fmaxf(v[i].z, v[i].w)));
  }
#pragma unroll
  for (int o = 32; o; o >>= 1) mx = fmaxf(mx, __shfl_xor(mx, o, 64));
  __shared__ float smax[4], ssum[4];
  const int w = t >> 6;
  if ((t & 63) == 0) smax[w] = mx;
  __syncthreads();
  mx = fmaxf(fmaxf(smax[0], smax[1]), fmaxf(smax[2], smax[3]));
  float s = 0.f;
#pragma unroll
  for (int i = 0; i < 4; ++i) {
    v[i].x = __expf(v[i].x - mx);
    v[i].y = __expf(v[i].y - mx);
    v[i].z = __expf(v[i].z - mx);
    v[i].w = __expf(v[i].w - mx);
    s += (v[i].x + v[i].y) + (v[i].z + v[i].w);
  }
#pragma unroll
  for (int o = 32; o; o >>= 1) s += __shfl_xor(s, o, 64);
  if ((t & 63) == 0) ssum[w] = s;
  __syncthreads();
  const float inv = 1.0f / (ssum[0] + ssum[1] + ssum[2] + ssum[3]);
#pragma unroll
  for (int i = 0; i < 4; ++i) {
    v[i].x *= inv; v[i].y *= inv; v[i].z *= inv; v[i].w *= inv;
    r4[t + i * 256] = v[i];
  }
}

extern "C" void kernel_launch(void* const* d_in, const int* in_sizes, int n_in,
                              void* d_out, int out_size, void* d_ws, size_t ws_size,
                              hipStream_t stream) {
  const float* out_state = (const float*)d_in[0];  // [4096,1024]
  const float* history   = (const float*)d_in[1];  // [4096,1024]
  const float* W         = (const float*)d_in[2];  // [1024,1024]
  float* out = (float*)d_out;                      // [4096,4096]

  unsigned short* Hh = (unsigned short*)d_ws;                 // 4096x1024 each
  unsigned short* Hl = Hh + (size_t)4096 * 1024;
  unsigned short* Wh = Hl + (size_t)4096 * 1024;              // 1024x1024
  unsigned short* Wl = Wh + (size_t)1024 * 1024;
  unsigned short* Ah = Wl + (size_t)1024 * 1024;              // 4096x1024
  unsigned short* Al = Ah + (size_t)4096 * 1024;
  unsigned short* Ph = Al + (size_t)4096 * 1024;              // 4096x1024
  unsigned short* Pl = Ph + (size_t)4096 * 1024;
  float* P32 = (float*)(Pl + (size_t)4096 * 1024);            // 2 x 4096x1024 fp32

  split_all<<<9216, 256, 0, stream>>>(history, W, out_state, Hh, Hl, Wh, Wl, Ah, Al);

  // stage-1: split-K=2 proj (unchanged). 512 blocks, 2 blocks/CU.
  gemm_p<<<512, 512, 0, stream>>>(Hh, Hl, Wh, Wl, P32);
  reduce_split<<<4096, 256, 0, stream>>>(P32, P32 + (size_t)4096 * 1024, Ph, Pl);

  // stage-2: energies, 8-phase template over 48 virtual K-tiles. 256 blocks.
  gemm_e<<<256, 512, 0, stream>>>(Ah, Al, Ph, Pl, out);

  softmax_inplace<<<4096, 256, 0, stream>>>(out, 4096);
}

// Round 14
// 257.464 us; speedup vs baseline: 1.0634x; 1.0634x over previous
//
#include <hip/hip_runtime.h>
#include <hip/hip_bf16.h>

// Attn: energies = out_state @ (history @ W.T).T ; softmax rows.
// S2=S1=4096, N=1024. fp32 in/out. bf16 hi/lo GEMM, 3 products
// (Ah.Bh + Al.Bh + Ah.Bl), 4 separate arrays (R15: -33% staged bytes).
// R23 post-mortem: 8-phase virtual-K port regressed (+50% staged bytes,
//   FETCH 49->74 MB) -- 9th schedule-surgery failure; family is byte-paced.
//   gemm_e reverted to R22-exact (106.7 us best: 32x32 MFMA, deferred
//   al x bh product into next slab's refill window, SGB-pinned interleave).
// R24: structural cleanup. gemm_p goes FULL-K single dispatch (32 slabs,
//   256 blocks, 1 block/CU) writing Ph/Pl directly in the epilogue;
//   reduce_split + P32 round-trip deleted (saves ~9 us dispatch + ~48 MB
//   HBM). Split-K never actually paid (R17's gain == reduce cost). Also
//   surfaces gemm_p near the top-5 cutoff for direct profiling.

typedef __bf16 bf16x8 __attribute__((ext_vector_type(8)));
typedef float f32x4 __attribute__((ext_vector_type(4)));
typedef float f32x16 __attribute__((ext_vector_type(16)));
typedef unsigned short u16x4 __attribute__((ext_vector_type(4)));

__device__ __forceinline__ unsigned short f2bf(float x) {
  unsigned int u = __float_as_uint(x);
  u += 0x7fffu + ((u >> 16) & 1u);   // RNE
  return (unsigned short)(u >> 16);
}
__device__ __forceinline__ float bf2f(unsigned short h) {
  return __uint_as_float(((unsigned int)h) << 16);
}

__device__ __forceinline__ void async_copy_16(void* lds, const void* gsrc) {
  __builtin_amdgcn_global_load_lds(
      (const __attribute__((address_space(1))) void*)gsrc,
      (__attribute__((address_space(3))) void*)lds, 16, 0, 0);
}

__device__ __forceinline__ void barrier_fenced() {
  asm volatile("" ::: "memory");
  __builtin_amdgcn_s_barrier();
  asm volatile("" ::: "memory");
}

// Fused split: fp32 X[rows x 1024] -> Yh, Yl bf16 (hi + residual-lo) for
// history (4096), W (1024), out_state (4096) in one launch (grid 9216).
__global__ __launch_bounds__(256)
void split_all(const float* __restrict__ H, const float* __restrict__ W,
               const float* __restrict__ OS,
               unsigned short* __restrict__ Hh, unsigned short* __restrict__ Hl,
               unsigned short* __restrict__ Wh, unsigned short* __restrict__ Wl,
               unsigned short* __restrict__ Ah, unsigned short* __restrict__ Al) {
  const int b = blockIdx.x;
  const float* X; unsigned short *Yh, *Yl; size_t row;
  if (b < 4096)      { X = H;  Yh = Hh; Yl = Hl; row = b; }
  else if (b < 5120) { X = W;  Yh = Wh; Yl = Wl; row = b - 4096; }
  else               { X = OS; Yh = Ah; Yl = Al; row = b - 5120; }
  const int c4 = threadIdx.x;
  float4 x = ((const float4*)(X + row * 1024))[c4];
  float xs[4] = {x.x, x.y, x.z, x.w};
  u16x4 h, l;
#pragma unroll
  for (int i = 0; i < 4; ++i) {
    unsigned short hh = f2bf(xs[i]);
    h[i] = hh;
    l[i] = f2bf(xs[i] - bf2f(hh));
  }
  ((u16x4*)(Yh + row * 1024))[c4] = h;
  ((u16x4*)(Yl + row * 1024))[c4] = l;
}

// ===================== stage-2: energies (R22-exact) ========================
// C[4096,4096] = Ah.Bh^T + Al.Bh^T + Ah.Bl^T, K=1024. 256x256 tile, 8 waves
// (2x4), wave tile 128x64 = 4x2 frags of 32x32. NBUF=2. 5 windows/slab,
// al x bh deferred one slab (fills refill window), SGB-pinned interleave.
__global__ __launch_bounds__(512, 2)
void gemm_e(const unsigned short* __restrict__ Ah, const unsigned short* __restrict__ Al,
            const unsigned short* __restrict__ Bh, const unsigned short* __restrict__ Bl,
            float* __restrict__ C) {
  constexpr int NTILES = 32;
  __shared__ unsigned short AhS[2][256 * 32];
  __shared__ unsigned short AlS[2][256 * 32];
  __shared__ unsigned short BhS[2][256 * 32];
  __shared__ unsigned short BlS[2][256 * 32];

  const int tid = threadIdx.x;
  const int w = tid >> 6;
  const int lane = tid & 63;
  const int wm = w >> 2, wn = w & 3;
  const int lr = lane & 31;              // row within 32-group
  const int ls = lane >> 5;              // k-segment (8 bf16)

  // XCD swizzle: grid 256 = 8 XCDs x 32; bijective
  const int id = blockIdx.x;
  const int xcd = id & 7;
  const int j = id >> 3;
  const int bm = ((xcd % 4) * 4 + (j % 4)) * 256;
  const int bn = ((xcd / 4) * 8 + (j / 4)) * 256;

  const unsigned short *pah, *pal, *pbh, *pbl;
  {
    const size_t ra = (size_t)(bm + w * 32 + lr) * 1024 + ls * 8;
    pah = Ah + ra; pal = Al + ra;
    const size_t rb = (size_t)(bn + w * 32 + lr) * 1024 + ls * 8;
    pbh = Bh + rb; pbl = Bl + rb;
  }

  f32x16 acc[4][2] = {};

  auto stageAh = [&](int buf, int t) {
#pragma unroll
    for (int h = 0; h < 2; ++h)
      async_copy_16(&AhS[buf][w * 1024 + h * 512], pah + t * 32 + h * 16);
  };
  auto stageAl = [&](int buf, int t) {
#pragma unroll
    for (int h = 0; h < 2; ++h)
      async_copy_16(&AlS[buf][w * 1024 + h * 512], pal + t * 32 + h * 16);
  };
  auto stageBh = [&](int buf, int t) {
#pragma unroll
    for (int h = 0; h < 2; ++h)
      async_copy_16(&BhS[buf][w * 1024 + h * 512], pbh + t * 32 + h * 16);
  };
  auto stageBl = [&](int buf, int t) {
#pragma unroll
    for (int h = 0; h < 2; ++h)
      async_copy_16(&BlS[buf][w * 1024 + h * 512], pbl + t * 32 + h * 16);
  };
  auto LDAh = [&](int buf, int g, int h) { return *(const bf16x8*)&AhS[buf][g * 1024 + h * 512 + lane * 8]; };
  auto LDAl = [&](int buf, int g, int h) { return *(const bf16x8*)&AlS[buf][g * 1024 + h * 512 + lane * 8]; };
  auto LDBh = [&](int buf, int g, int h) { return *(const bf16x8*)&BhS[buf][g * 1024 + h * 512 + lane * 8]; };
  auto LDBl = [&](int buf, int g, int h) { return *(const bf16x8*)&BlS[buf][g * 1024 + h * 512 + lane * 8]; };

  // fragment registers live across slabs (al/bhp feed the deferred product).
  bf16x8 ah[4][2], bh[2][2], bl[2][2];
  bf16x8 al[4][2] = {};                  // zeros: slab-0 deferred MFMA adds 0
  bf16x8 bhp[2][2] = {};

  // prologue: stage slab 0, full drain, publish.
  stageAh(0, 0); stageBh(0, 0); stageAl(0, 0); stageBl(0, 0);
  asm volatile("s_waitcnt vmcnt(0)" ::: "memory");
  barrier_fenced();

#pragma unroll 1
  for (int t = 0; t < NTILES; ++t) {
    const int buf = t & 1, nb = buf ^ 1;
    const bool st = (t + 1 < NTILES);

    // ---- w0: reads ah[0..4)+bh(t) (12); stage Ah(t+1); DEFERRED 16 MFMA
    //      al(t-1) x bhp(t-1). SGB pins 3-read:4-MFMA interleave.
#pragma unroll
    for (int mt = 0; mt < 4; ++mt)
#pragma unroll
      for (int h = 0; h < 2; ++h) ah[mt][h] = LDAh(buf, wm * 4 + mt, h);
#pragma unroll
    for (int nt = 0; nt < 2; ++nt)
#pragma unroll
      for (int h = 0; h < 2; ++h) bh[nt][h] = LDBh(buf, wn * 2 + nt, h);
    if (st) stageAh(nb, t + 1);
    __builtin_amdgcn_s_setprio(1);
#pragma unroll
    for (int h = 0; h < 2; ++h)
#pragma unroll
      for (int mt = 0; mt < 4; ++mt)
#pragma unroll
        for (int nt = 0; nt < 2; ++nt)
          acc[mt][nt] = __builtin_amdgcn_mfma_f32_32x32x16_bf16(al[mt][h], bhp[nt][h], acc[mt][nt], 0, 0, 0);
    __builtin_amdgcn_s_setprio(0);
    __builtin_amdgcn_sched_group_barrier(0x10, 2, 0);   // 2 global_load_lds
#pragma unroll
    for (int g = 0; g < 4; ++g) {
      __builtin_amdgcn_sched_group_barrier(0x100, 3, 0); // 3 ds_read
      __builtin_amdgcn_sched_group_barrier(0x8, 4, 0);   // 4 MFMA
    }
    barrier_fenced();

    // ---- w1: reads bl (4); stage Bh(t+1); 8 MFMA ah[0..2) x bh ----
#pragma unroll
    for (int nt = 0; nt < 2; ++nt)
#pragma unroll
      for (int h = 0; h < 2; ++h) bl[nt][h] = LDBl(buf, wn * 2 + nt, h);
    if (st) stageBh(nb, t + 1);
    __builtin_amdgcn_s_setprio(1);
#pragma unroll
    for (int h = 0; h < 2; ++h)
#pragma unroll
      for (int mt = 0; mt < 2; ++mt)
#pragma unroll
        for (int nt = 0; nt < 2; ++nt)
          acc[mt][nt] = __builtin_amdgcn_mfma_f32_32x32x16_bf16(ah[mt][h], bh[nt][h], acc[mt][nt], 0, 0, 0);
    __builtin_amdgcn_s_setprio(0);
    __builtin_amdgcn_sched_group_barrier(0x10, 2, 0);
#pragma unroll
    for (int g = 0; g < 4; ++g) {
      __builtin_amdgcn_sched_group_barrier(0x100, 1, 0);
      __builtin_amdgcn_sched_group_barrier(0x8, 2, 0);
    }
    barrier_fenced();

    // ---- w2: reads al[0..2) (4); stage Al(t+1); 8 MFMA ah[2..4) x bh ----
#pragma unroll
    for (int mt = 0; mt < 2; ++mt)
#pragma unroll
      for (int h = 0; h < 2; ++h) al[mt][h] = LDAl(buf, wm * 4 + mt, h);
    if (st) stageAl(nb, t + 1);
    __builtin_amdgcn_s_setprio(1);
#pragma unroll
    for (int h = 0; h < 2; ++h)
#pragma unroll
      for (int mt = 2; mt < 4; ++mt)
#pragma unroll
        for (int nt = 0; nt < 2; ++nt)
          acc[mt][nt] = __builtin_amdgcn_mfma_f32_32x32x16_bf16(ah[mt][h], bh[nt][h], acc[mt][nt], 0, 0, 0);
    __builtin_amdgcn_s_setprio(0);
    __builtin_amdgcn_sched_group_barrier(0x10, 2, 0);
#pragma unroll
    for (int g = 0; g < 4; ++g) {
      __builtin_amdgcn_sched_group_barrier(0x100, 1, 0);
      __builtin_amdgcn_sched_group_barrier(0x8, 2, 0);
    }
    barrier_fenced();

    // ---- w3: reads al[2..4) (4); stage Bl(t+1); 8 MFMA ah[0..2) x bl ----
#pragma unroll
    for (int mt = 2; mt < 4; ++mt)
#pragma unroll
      for (int h = 0; h < 2; ++h) al[mt][h] = LDAl(buf, wm * 4 + mt, h);
    if (st) stageBl(nb, t + 1);
    __builtin_amdgcn_s_setprio(1);
#pragma unroll
    for (int h = 0; h < 2; ++h)
#pragma unroll
      for (int mt = 0; mt < 2; ++mt)
#pragma unroll
        for (int nt = 0; nt < 2; ++nt)
          acc[mt][nt] = __builtin_amdgcn_mfma_f32_32x32x16_bf16(ah[mt][h], bl[nt][h], acc[mt][nt], 0, 0, 0);
    __builtin_amdgcn_s_setprio(0);
    __builtin_amdgcn_sched_group_barrier(0x10, 2, 0);
#pragma unroll
    for (int g = 0; g < 4; ++g) {
      __builtin_amdgcn_sched_group_barrier(0x100, 1, 0);
      __builtin_amdgcn_sched_group_barrier(0x8, 2, 0);
    }
    barrier_fenced();

    // ---- w4: 8 MFMA ah[2..4) x bl; save bh -> bhp; boundary drain ----
    __builtin_amdgcn_s_setprio(1);
#pragma unroll
    for (int h = 0; h < 2; ++h)
#pragma unroll
      for (int mt = 2; mt < 4; ++mt)
#pragma unroll
        for (int nt = 0; nt < 2; ++nt)
          acc[mt][nt] = __builtin_amdgcn_mfma_f32_32x32x16_bf16(ah[mt][h], bl[nt][h], acc[mt][nt], 0, 0, 0);
    __builtin_amdgcn_s_setprio(0);
#pragma unroll
    for (int nt = 0; nt < 2; ++nt)
#pragma unroll
      for (int h = 0; h < 2; ++h) bhp[nt][h] = bh[nt][h];

    __builtin_amdgcn_sched_barrier(0);
    asm volatile("s_waitcnt vmcnt(0) lgkmcnt(0)" ::: "memory");
    barrier_fenced();
  }

  // final deferred product: al(31) x bhp(31)
#pragma unroll
  for (int h = 0; h < 2; ++h)
#pragma unroll
    for (int mt = 0; mt < 4; ++mt)
#pragma unroll
      for (int nt = 0; nt < 2; ++nt)
        acc[mt][nt] = __builtin_amdgcn_mfma_f32_32x32x16_bf16(al[mt][h], bhp[nt][h], acc[mt][nt], 0, 0, 0);

  // Epilogue. 32x32 C/D: col = lane&31, row = (reg&3)+8*(reg>>2)+4*(lane>>5).
  const int cm0 = bm + wm * 128;
  const int cn0 = bn + wn * 64;
#pragma unroll
  for (int mt = 0; mt < 4; ++mt)
#pragma unroll
    for (int nt = 0; nt < 2; ++nt) {
      const int col = cn0 + nt * 32 + lr;
      const int row0 = cm0 + mt * 32 + ls * 4;
#pragma unroll
      for (int reg = 0; reg < 16; ++reg) {
        const int row = row0 + (reg & 3) + 8 * (reg >> 2);
        C[(size_t)row * 4096 + col] = acc[mt][nt][reg];
      }
    }
}

// ============== stage-1: proj (full-K, direct Ph/Pl epilogue) ===============
// Ph,Pl[4096,1024] = hi/lo split of Ah.Bh^T + Al.Bh^T + Ah.Bl^T, K=1024.
// 128x128 tile, 8 waves (2x4), wave tile 64x32. NBUF=2 (64 KB), 32 slabs,
// 2 lockstep windows (R20 body). 256 blocks, 1 block/CU. No split-K: the
// reduce pass + P32 round-trip (~9 us + 48 MB HBM) are eliminated.
__global__ __launch_bounds__(512, 2)
void gemm_p(const unsigned short* __restrict__ Ah, const unsigned short* __restrict__ Al,
            const unsigned short* __restrict__ Bh, const unsigned short* __restrict__ Bl,
            unsigned short* __restrict__ Ph, unsigned short* __restrict__ Pl) {
  constexpr int MT = 4, NT = 2, NTILES = 32;
  __shared__ unsigned short AhS[2][128 * 32];
  __shared__ unsigned short AlS[2][128 * 32];
  __shared__ unsigned short BhS[2][128 * 32];
  __shared__ unsigned short BlS[2][128 * 32];

  const int tid = threadIdx.x;
  const int w = tid >> 6;
  const int lane = tid & 63;
  const int wm = w >> 2, wn = w & 3;
  const int lr = lane & 15;
  const int ls = lane >> 4;

  // XCD swizzle: grid 256 = 8 XCDs x 32; bm 32 values, bn 8 values; bijective
  const int id = blockIdx.x;
  const int xcd = id & 7;
  const int j = id >> 3;
  const int bm = ((xcd % 4) * 8 + (j % 8)) * 128;
  const int bn = ((xcd / 4) * 4 + (j / 8)) * 128;

  const unsigned short *pah, *pal, *pbh, *pbl;
  {
    const size_t ra = (size_t)(bm + w * 16 + lr) * 1024 + ls * 8;
    pah = Ah + ra; pal = Al + ra;
    const size_t rb = (size_t)(bn + w * 16 + lr) * 1024 + ls * 8;
    pbh = Bh + rb; pbl = Bl + rb;
  }

  f32x4 acc[MT][NT] = {};

  auto stage_all = [&](int buf, int t) {
    async_copy_16(&AhS[buf][w * 512], pah + t * 32);
    async_copy_16(&BhS[buf][w * 512], pbh + t * 32);
    async_copy_16(&BlS[buf][w * 512], pbl + t * 32);
    async_copy_16(&AlS[buf][w * 512], pal + t * 32);
  };
  auto LDAh = [&](int buf, int g) { return *(const bf16x8*)&AhS[buf][g * 512 + ls * 128 + lr * 8]; };
  auto LDAl = [&](int buf, int g) { return *(const bf16x8*)&AlS[buf][g * 512 + ls * 128 + lr * 8]; };
  auto LDBh = [&](int buf, int g) { return *(const bf16x8*)&BhS[buf][g * 512 + ls * 128 + lr * 8]; };
  auto LDBl = [&](int buf, int g) { return *(const bf16x8*)&BlS[buf][g * 512 + ls * 128 + lr * 8]; };

  stage_all(0, 0);
  asm volatile("s_waitcnt vmcnt(0)" ::: "memory");
  barrier_fenced();

#pragma unroll 1
  for (int t = 0; t < NTILES; ++t) {
    const int buf = t & 1, nb = buf ^ 1;
    const bool st = (t + 1 < NTILES);
    bf16x8 ah[4], al[4], bh[2], bl[2];

    // w0: Ah,Bh,Bl reads; issue slab t+1; 16 MFMA (ah.bh + ah.bl)
#pragma unroll
    for (int mt = 0; mt < 4; ++mt) ah[mt] = LDAh(buf, wm * MT + mt);
#pragma unroll
    for (int nt = 0; nt < 2; ++nt) bh[nt] = LDBh(buf, wn * NT + nt);
#pragma unroll
    for (int nt = 0; nt < 2; ++nt) bl[nt] = LDBl(buf, wn * NT + nt);
    if (st) stage_all(nb, t + 1);
    barrier_fenced();
    asm volatile("s_waitcnt lgkmcnt(0)" ::: "memory");
    __builtin_amdgcn_s_setprio(1);
#pragma unroll
    for (int mt = 0; mt < 4; ++mt)
#pragma unroll
      for (int nt = 0; nt < 2; ++nt)
        acc[mt][nt] = __builtin_amdgcn_mfma_f32_16x16x32_bf16(ah[mt], bh[nt], acc[mt][nt], 0, 0, 0);
#pragma unroll
    for (int mt = 0; mt < 4; ++mt)
#pragma unroll
      for (int nt = 0; nt < 2; ++nt)
        acc[mt][nt] = __builtin_amdgcn_mfma_f32_16x16x32_bf16(ah[mt], bl[nt], acc[mt][nt], 0, 0, 0);
    __builtin_amdgcn_s_setprio(0);
    barrier_fenced();

    // w1: Al reads; 8 MFMA (al.bh)
#pragma unroll
    for (int mt = 0; mt < 4; ++mt) al[mt] = LDAl(buf, wm * MT + mt);
    barrier_fenced();
    asm volatile("s_waitcnt lgkmcnt(0)" ::: "memory");
    __builtin_amdgcn_s_setprio(1);
#pragma unroll
    for (int mt = 0; mt < 4; ++mt)
#pragma unroll
      for (int nt = 0; nt < 2; ++nt)
        acc[mt][nt] = __builtin_amdgcn_mfma_f32_16x16x32_bf16(al[mt], bh[nt], acc[mt][nt], 0, 0, 0);
    __builtin_amdgcn_s_setprio(0);

    asm volatile("s_waitcnt vmcnt(0) lgkmcnt(0)" ::: "memory");
    barrier_fenced();
  }

  // Epilogue: hi/lo split write. 16x16 C/D: col = lane&15, row = (lane>>4)*4+reg.
  const int cm0 = bm + wm * 64;
  const int cn0 = bn + wn * 32;
#pragma unroll
  for (int mt = 0; mt < MT; ++mt)
#pragma unroll
    for (int nt = 0; nt < NT; ++nt) {
      const int col = cn0 + nt * 16 + lr;
      const int row0 = cm0 + mt * 16 + ls * 4;
#pragma unroll
      for (int r = 0; r < 4; ++r) {
        const float p = acc[mt][nt][r];
        const unsigned short h = f2bf(p);
        const unsigned short l = f2bf(p - bf2f(h));
        const size_t base = (size_t)(row0 + r) * 1024 + col;
        Ph[base] = h;
        Pl[base] = l;
      }
    }
}

// In-place row softmax, N=4096, one block per row, 16 floats/thread in regs.
__global__ __launch_bounds__(256)
void softmax_inplace(float* __restrict__ C, int N) {
  float4* r4 = (float4*)(C + (size_t)blockIdx.x * N);
  const int t = threadIdx.x;
  float4 v[4];
  float mx = -3.0e38f;
#pragma unroll
  for (int i = 0; i < 4; ++i) {
    v[i] = r4[t + i * 256];
    mx = fmaxf(mx, fmaxf(fmaxf(v[i].x, v[i].y), fmaxf(v[i].z, v[i].w)));
  }
#pragma unroll
  for (int o = 32; o; o >>= 1) mx = fmaxf(mx, __shfl_xor(mx, o, 64));
  __shared__ float smax[4], ssum[4];
  const int w = t >> 6;
  if ((t & 63) == 0) smax[w] = mx;
  __syncthreads();
  mx = fmaxf(fmaxf(smax[0], smax[1]), fmaxf(smax[2], smax[3]));
  float s = 0.f;
#pragma unroll
  for (int i = 0; i < 4; ++i) {
    v[i].x = __expf(v[i].x - mx);
    v[i].y = __expf(v[i].y - mx);
    v[i].z = __expf(v[i].z - mx);
    v[i].w = __expf(v[i].w - mx);
    s += (v[i].x + v[i].y) + (v[i].z + v[i].w);
  }
#pragma unroll
  for (int o = 32; o; o >>= 1) s += __shfl_xor(s, o, 64);
  if ((t & 63) == 0) ssum[w] = s;
  __syncthreads();
  const float inv = 1.0f / (ssum[0] + ssum[1] + ssum[2] + ssum[3]);
#pragma unroll
  for (int i = 0; i < 4; ++i) {
    v[i].x *= inv; v[i].y *= inv; v[i].z *= inv; v[i].w *= inv;
    r4[t + i * 256] = v[i];
  }
}

extern "C" void kernel_launch(void* const* d_in, const int* in_sizes, int n_in,
                              void* d_out, int out_size, void* d_ws, size_t ws_size,
                              hipStream_t stream) {
  const float* out_state = (const float*)d_in[0];  // [4096,1024]
  const float* history   = (const float*)d_in[1];  // [4096,1024]
  const float* W         = (const float*)d_in[2];  // [1024,1024]
  float* out = (float*)d_out;                      // [4096,4096]

  unsigned short* Hh = (unsigned short*)d_ws;                 // 4096x1024 each
  unsigned short* Hl = Hh + (size_t)4096 * 1024;
  unsigned short* Wh = Hl + (size_t)4096 * 1024;              // 1024x1024
  unsigned short* Wl = Wh + (size_t)1024 * 1024;
  unsigned short* Ah = Wl + (size_t)1024 * 1024;              // 4096x1024
  unsigned short* Al = Ah + (size_t)4096 * 1024;
  unsigned short* Ph = Al + (size_t)4096 * 1024;              // 4096x1024
  unsigned short* Pl = Ph + (size_t)4096 * 1024;

  split_all<<<9216, 256, 0, stream>>>(history, W, out_state, Hh, Hl, Wh, Wl, Ah, Al);

  // stage-1: full-K proj writing Ph/Pl directly. 256 blocks, 1 block/CU.
  gemm_p<<<256, 512, 0, stream>>>(Hh, Hl, Wh, Wl, Ph, Pl);

  // stage-2: energies (R22-exact). 256 blocks.
  gemm_e<<<256, 512, 0, stream>>>(Ah, Al, Ph, Pl, out);

  softmax_inplace<<<4096, 256, 0, stream>>>(out, 4096);
}